// Round 1
// 208.200 us; speedup vs baseline: 1.1030x; 1.1030x over previous
//
#include <hip/hip_runtime.h>
#include <hip/hip_bf16.h>

// Sizes (fixed for this problem)
#define B_ 4096
#define D_ 1024
#define E_ 8
#define H_ 1024
#define A_ 512
#define PB 6144       // padded bucketed rows: per-expert buckets 256-aligned
#define NTT 24        // PB/256 row tiles
#define FB_CAP 128    // fallback slots per expert
#define FROWS (E_ * FB_CAP)   // 1024 fallback slots
#define KSPLIT 4
#define MARGIN 3.0e-3f

typedef __attribute__((ext_vector_type(8))) short s16x8;
typedef __attribute__((ext_vector_type(4))) float f32x4;

__device__ __forceinline__ unsigned short f2bf(float f) {
    __hip_bfloat16 h = __float2bfloat16(f);
    return *reinterpret_cast<unsigned short*>(&h);
}
__device__ __forceinline__ float bf2f(unsigned short u) {
    return __uint_as_float(((unsigned int)u) << 16);
}
__device__ __forceinline__ void gload16(const void* g, void* l) {
    __builtin_amdgcn_global_load_lds(
        (const __attribute__((address_space(1))) unsigned int*)g,
        (__attribute__((address_space(3))) unsigned int*)l, 16, 0, 0);
}

// swizzled source chunk offset (halves) for lane l (8-row stripes, 16B chunks)
__device__ __forceinline__ int a_src_chunk(int lane) { return (((lane & 7) ^ (lane >> 3)) * 8); }

// rotated LDS column for transpose tiles (conflict-free both phases)
__device__ __forceinline__ int trc(int r, int c) { return (c + r + (r >> 2)) & 63; }

// ---- 256-thread transpose: 128(k) x 64(n) fp32 [k][n] -> bf16 [n][k], dst row stride 1024 ----
__device__ __forceinline__ void tr_tile_256(const float* __restrict__ src, int Nsrc,
                                            unsigned short* __restrict__ dst, float* T) {
    const int t = threadIdx.x;
    const int c4 = (t & 15) * 4, r0 = t >> 4;
#pragma unroll
    for (int i = 0; i < 8; ++i) {
        const int r = r0 + i * 16;
        const float4 v = *(const float4*)&src[(size_t)r * Nsrc + c4];
        float* Tr = T + r * 64;
        Tr[trc(r, c4 + 0)] = v.x; Tr[trc(r, c4 + 1)] = v.y;
        Tr[trc(r, c4 + 2)] = v.z; Tr[trc(r, c4 + 3)] = v.w;
    }
    __syncthreads();
    const int k4 = (t & 31) * 4, n0 = t >> 5;
#pragma unroll
    for (int i = 0; i < 8; ++i) {
        const int n = n0 + i * 8;
        ushort4 o;
        o.x = f2bf(T[(k4 + 0) * 64 + trc(k4 + 0, n)]);
        o.y = f2bf(T[(k4 + 1) * 64 + trc(k4 + 1, n)]);
        o.z = f2bf(T[(k4 + 2) * 64 + trc(k4 + 2, n)]);
        o.w = f2bf(T[(k4 + 3) * 64 + trc(k4 + 3, n)]);
        *(ushort4*)&dst[(size_t)n * 1024 + k4] = o;
    }
}

// ---- 512-thread transpose: 256(k) x 64(n) fp32 [k][n] -> bf16 [n][k], dst row stride 1024 ----
__device__ __forceinline__ void tr_tile_512(const float* __restrict__ src, int Nsrc,
                                            unsigned short* __restrict__ dst, float* T) {
    const int t = threadIdx.x;
    const int c4 = (t & 15) * 4, r0 = t >> 4;
#pragma unroll
    for (int i = 0; i < 8; ++i) {
        const int r = r0 + i * 32;
        const float4 v = *(const float4*)&src[(size_t)r * Nsrc + c4];
        float* Tr = T + r * 64;
        Tr[trc(r, c4 + 0)] = v.x; Tr[trc(r, c4 + 1)] = v.y;
        Tr[trc(r, c4 + 2)] = v.z; Tr[trc(r, c4 + 3)] = v.w;
    }
    __syncthreads();
    const int k4 = (t & 63) * 4, n0 = t >> 6;
#pragma unroll
    for (int i = 0; i < 8; ++i) {
        const int n = n0 + i * 8;
        ushort4 o;
        o.x = f2bf(T[(k4 + 0) * 64 + trc(k4 + 0, n)]);
        o.y = f2bf(T[(k4 + 1) * 64 + trc(k4 + 1, n)]);
        o.z = f2bf(T[(k4 + 2) * 64 + trc(k4 + 2, n)]);
        o.w = f2bf(T[(k4 + 3) * 64 + trc(k4 + 3, n)]);
        *(ushort4*)&dst[(size_t)n * 1024 + k4] = o;
    }
}

// ---------------- prep: bucketize + state->bf16 + head/We1 weight transpose->bf16 ----------------
// grid: [0]=bucketize, [1..4096]=state cvt, [4097..4352]=head transpose, [4353..5376]=We1 transpose
__global__ void k_prep(const float* __restrict__ x, unsigned short* __restrict__ y,
                       const float* __restrict__ Wo1, const float* __restrict__ Wt1,
                       unsigned short* __restrict__ Wbf,
                       const float* __restrict__ We1, unsigned short* __restrict__ We1t,
                       const int* __restrict__ sel, int* __restrict__ tile_expert,
                       int* __restrict__ rowlist, int* __restrict__ pos_of_row,
                       int* __restrict__ rowlist2, int* __restrict__ cur2) {
    __shared__ float T[128 * 64];
    const int t = threadIdx.x;
    const int bid = blockIdx.x;
    if (bid >= 4353) {                       // We1 transpose: 1024 blocks
        const int q = bid - 4353;
        const int e = q >> 7, r = q & 127, kt = r >> 4, ntb = r & 15;
        tr_tile_256(We1 + (size_t)e * 1048576 + (size_t)(kt * 128) * 1024 + ntb * 64, 1024,
                    We1t + (size_t)e * 1048576 + (size_t)(ntb * 64) * 1024 + kt * 128, T);
        return;
    }
    if (bid >= 4097) {                       // head-weight transpose: 256 blocks
        const int q = bid - 4097;
        const int m = q >> 7, r = q & 127, kt = r >> 4, ntb = r & 15;
        const float* src = (m ? Wt1 : Wo1) + (size_t)(kt * 128) * 1024 + ntb * 64;
        tr_tile_256(src, 1024, Wbf + (size_t)(m * 1024 + ntb * 64) * 1024 + kt * 128, T);
        return;
    }
    if (bid > 0) {                           // state -> bf16
        int i = (bid - 1) * 256 + t;
        float4 v = ((const float4*)x)[i];
        ushort4 o;
        o.x = f2bf(v.x); o.y = f2bf(v.y); o.z = f2bf(v.z); o.w = f2bf(v.w);
        ((ushort4*)y)[i] = o;
        return;
    }
    __shared__ int scnt[E_], soff[E_], scur[E_];
    if (t < E_) { scnt[t] = 0; scur[t] = 0; cur2[t] = 0; }
    for (int i = t; i < PB; i += 256) rowlist[i] = -1;
    for (int i = t; i < FROWS; i += 256) rowlist2[i] = -1;
    __syncthreads();
    for (int b = t; b < B_; b += 256) {
        int e = sel[b]; e = e < 0 ? 0 : (e >= E_ ? E_ - 1 : e);
        atomicAdd(&scnt[e], 1);
    }
    __syncthreads();
    if (t == 0) {
        int off = 0;
        for (int e = 0; e < E_; ++e) {
            soff[e] = off;
            int tiles = (scnt[e] + 255) >> 8;
            for (int k = 0; k < tiles; ++k) tile_expert[(off >> 8) + k] = e;
            off += tiles << 8;
        }
        for (int k = off >> 8; k < NTT; ++k) tile_expert[k] = -1;
    }
    __syncthreads();
    for (int b = t; b < B_; b += 256) {
        int e = sel[b]; e = e < 0 ? 0 : (e >= E_ ? E_ - 1 : e);
        int pos = atomicAdd(&scur[e], 1);
        int p = soff[e] + pos; if (p >= PB) p = PB - 1;
        rowlist[p] = b;
        pos_of_row[b] = p;
    }
}

// ======== unified GEMM core v3: 256xTN tile, 8 waves (4x2), BK=64, A+B^T both via global_load_lds ========
// Bt: transposed bf16 weights, [n][k] rows with row stride Kg halves (pre-offset to tile row 0).
template<int TN>
__device__ __forceinline__ void gemm3(
    const unsigned short* __restrict__ g0, const unsigned short* __restrict__ g1,
    const unsigned short* __restrict__ g2, const unsigned short* __restrict__ g3,
    const unsigned short* __restrict__ Bt, int Kg, const float* __restrict__ bp,
    unsigned short* __restrict__ Cbf, float* __restrict__ Cf, int Ncols, int relu,
    unsigned short* As, unsigned short* Bs)
{
    constexpr int NI = TN / 32;
    constexpr int BTH = TN * 64;      // halves per B buffer
    constexpr int BR = TN / 64;       // B gload rounds per thread per iter
    const int t = threadIdx.x, lane = t & 63, w = t >> 6;
    const int wr = w >> 1, wc = w & 1;
    const int aseg = w * 2048 + lane * 8;
    const int bseg = w * (BR * 512) + lane * 8;
    const int coffb = a_src_chunk(lane);
    const unsigned short* bsrc = Bt + (size_t)(w * BR * 8 + (lane >> 3)) * Kg + coffb;

    f32x4 acc[4][NI];
#pragma unroll
    for (int i = 0; i < 4; ++i)
#pragma unroll
        for (int j = 0; j < NI; ++j)
#pragma unroll
            for (int r = 0; r < 4; ++r) acc[i][j][r] = 0.f;

#define G_STAGE(IT, BUF) {                                                   \
        const int ko_ = (IT) * 64;                                           \
        const int oa_ = (BUF) * 16384 + aseg;                                \
        gload16(g0 + ko_, As + oa_);                                         \
        gload16(g1 + ko_, As + oa_ + 512);                                   \
        gload16(g2 + ko_, As + oa_ + 1024);                                  \
        gload16(g3 + ko_, As + oa_ + 1536);                                  \
        const int ob_ = (BUF) * BTH + bseg;                                  \
        _Pragma("unroll")                                                    \
        for (int j_ = 0; j_ < BR; ++j_)                                      \
            gload16(bsrc + ko_ + (size_t)(j_ * 8) * Kg, Bs + ob_ + j_ * 512); \
    }

    G_STAGE(0, 0);
    __syncthreads();

    for (int it = 0; it < 16; ++it) {
        const int cb = it & 1;
        if (it + 1 < 16) G_STAGE(it + 1, cb ^ 1);
        __builtin_amdgcn_s_setprio(1);
#pragma unroll
        for (int kq = 0; kq < 2; ++kq) {
            const int sc = kq * 4 + (lane >> 4);
            s16x8 af[4], bfr[NI];
#pragma unroll
            for (int mi = 0; mi < 4; ++mi) {
                const int ar = wr * 64 + mi * 16 + (lane & 15);
                af[mi] = *reinterpret_cast<const s16x8*>(
                    &As[cb * 16384 + ar * 64 + ((sc ^ (ar & 7)) << 3)]);
            }
#pragma unroll
            for (int ni = 0; ni < NI; ++ni) {
                const int br = wc * (TN / 2) + ni * 16 + (lane & 15);
                bfr[ni] = *reinterpret_cast<const s16x8*>(
                    &Bs[cb * BTH + br * 64 + ((sc ^ (br & 7)) << 3)]);
            }
#pragma unroll
            for (int mi = 0; mi < 4; ++mi)
#pragma unroll
                for (int ni = 0; ni < NI; ++ni)
                    acc[mi][ni] = __builtin_amdgcn_mfma_f32_16x16x32_bf16(
                        af[mi], bfr[ni], acc[mi][ni], 0, 0, 0);
        }
        __builtin_amdgcn_s_setprio(0);
        if (it + 1 < 16) __syncthreads();
    }
#undef G_STAGE

    const int cq = lane >> 4, cr = lane & 15;
#pragma unroll
    for (int ni = 0; ni < NI; ++ni) {
        const int col_l = wc * (TN / 2) + ni * 16 + cr;
        const float bv = bp[col_l];
#pragma unroll
        for (int mi = 0; mi < 4; ++mi) {
#pragma unroll
            for (int r = 0; r < 4; ++r) {
                const int row_l = wr * 64 + mi * 16 + cq * 4 + r;
                float v = acc[mi][ni][r] + bv;
                if (relu) v = fmaxf(v, 0.f);
                const size_t idx = (size_t)row_l * Ncols + col_l;
                if (Cbf) Cbf[idx] = f2bf(v);
                if (Cf)  Cf[idx] = v;
            }
        }
    }
}

// ---------------- D2: heads (128 blocks) + expert L1 (96 blocks), 256x256; + We2 transpose (512 blocks) ----------------
__global__ __launch_bounds__(512, 2)
void k_d2(const unsigned short* __restrict__ Sbf,
          const int* __restrict__ rowlist, const int* __restrict__ tile_expert,
          const unsigned short* __restrict__ Wbf,
          const float* __restrict__ bo1, const float* __restrict__ bt1,
          const unsigned short* __restrict__ We1t, const float* __restrict__ be1,
          const float* __restrict__ We2, unsigned short* __restrict__ We2t,
          unsigned short* __restrict__ hopt, unsigned short* __restrict__ hterm,
          unsigned short* __restrict__ h1) {
    __shared__ __align__(16) unsigned short SMEM[4 * 16384];   // 128 KiB
    unsigned short* As = SMEM;
    unsigned short* Bs = SMEM + 2 * 16384;
    const int bid = blockIdx.x;
    if (bid >= 224) {                      // We2 transpose on spare CUs
        const int q = bid - 224;
        const int e = q >> 6, r = q & 63, kt = r >> 4, ntb = r & 15;
        tr_tile_512(We2 + (size_t)e * 1048576 + (size_t)(kt * 256) * 1024 + ntb * 64, 1024,
                    We2t + (size_t)e * 1048576 + (size_t)(ntb * 64) * 1024 + kt * 256,
                    (float*)SMEM);
        return;
    }
    const int t = threadIdx.x, lane = t & 63, w = t >> 6;
    const int coff = a_src_chunk(lane);
    const int r0l = w * 32 + (lane >> 3);
    if (bid < 128) {
        const int nt = bid & 7, mt = bid >> 3;
        const unsigned short* g0 = Sbf + (size_t)(mt * 256 + r0l) * D_ + coff;
        const unsigned short* g1 = g0 + (size_t)8 * D_;
        const unsigned short* g2 = g0 + (size_t)16 * D_;
        const unsigned short* g3 = g0 + (size_t)24 * D_;
        int ntRow; const float* bp; unsigned short* C;
        if (nt < 4) { ntRow = nt * 256; bp = bo1 + nt * 256;
                      C = hopt + (size_t)(mt * 256) * H_ + nt * 256; }
        else { ntRow = 1024 + (nt - 4) * 256; bp = bt1 + (nt - 4) * 256;
               C = hterm + (size_t)(mt * 256) * H_ + (nt - 4) * 256; }
        gemm3<256>(g0, g1, g2, g3, Wbf + (size_t)ntRow * 1024, 1024, bp,
                   C, nullptr, H_, 1, As, Bs);
    } else {
        const int q = bid - 128, nt = q & 3, mt = q >> 2;
        const int e = tile_expert[mt]; if (e < 0) return;
        const int base = mt * 256;
        const int sub = rowlist[base]; if (sub < 0) return;
        int r0 = rowlist[base + r0l];      if (r0 < 0) r0 = sub;
        int r1 = rowlist[base + r0l + 8];  if (r1 < 0) r1 = sub;
        int r2 = rowlist[base + r0l + 16]; if (r2 < 0) r2 = sub;
        int r3 = rowlist[base + r0l + 24]; if (r3 < 0) r3 = sub;
        const unsigned short* g0 = Sbf + (size_t)r0 * D_ + coff;
        const unsigned short* g1 = Sbf + (size_t)r1 * D_ + coff;
        const unsigned short* g2 = Sbf + (size_t)r2 * D_ + coff;
        const unsigned short* g3 = Sbf + (size_t)r3 * D_ + coff;
        gemm3<256>(g0, g1, g2, g3,
                   We1t + (size_t)e * 1048576 + (size_t)(nt * 256) * 1024, 1024,
                   be1 + (size_t)e * H_ + nt * 256,
                   h1 + (size_t)(mt * 256) * H_ + nt * 256, nullptr, H_, 1, As, Bs);
    }
}

// ---------------- D3: expert L2, 256x128 (192 blocks); + We3 transpose (256 blocks) ----------------
__global__ __launch_bounds__(512, 2)
void k_d3(const unsigned short* __restrict__ h1, const int* __restrict__ tile_expert,
          const unsigned short* __restrict__ We2t, const float* __restrict__ be2,
          const float* __restrict__ We3, unsigned short* __restrict__ We3t,
          unsigned short* __restrict__ h2) {
    __shared__ __align__(16) unsigned short SMEM[2 * 16384 + 2 * 8192];  // 96 KiB
    unsigned short* As = SMEM;
    unsigned short* Bs = SMEM + 2 * 16384;
    const int bid = blockIdx.x;
    if (bid >= 192) {                      // We3 transpose on spare CUs
        const int q = bid - 192;
        const int e = q >> 5, r = q & 31, kt = r >> 3, ntb = r & 7;
        tr_tile_512(We3 + (size_t)e * 524288 + (size_t)(kt * 256) * 512 + ntb * 64, 512,
                    We3t + (size_t)e * 524288 + (size_t)(ntb * 64) * 1024 + kt * 256,
                    (float*)SMEM);
        return;
    }
    const int t = threadIdx.x, lane = t & 63, w = t >> 6;
    const int coff = a_src_chunk(lane);
    const int r0l = w * 32 + (lane >> 3);
    const int nt = bid & 7, mt = bid >> 3;
    const int e = tile_expert[mt]; if (e < 0) return;
    const unsigned short* g0 = h1 + (size_t)(mt * 256 + r0l) * H_ + coff;
    gemm3<128>(g0, g0 + (size_t)8 * H_, g0 + (size_t)16 * H_, g0 + (size_t)24 * H_,
               We2t + (size_t)e * 1048576 + (size_t)(nt * 128) * 1024, 1024,
               be2 + (size_t)e * H_ + nt * 128,
               h2 + (size_t)(mt * 256) * H_ + nt * 128, nullptr, H_, 1, As, Bs);
}

// ---------------- D5: expert L3, 256x64 -> fp32 logits, 192 blocks ----------------
__global__ __launch_bounds__(512, 2)
void k_d5(const unsigned short* __restrict__ h2, const int* __restrict__ tile_expert,
          const unsigned short* __restrict__ We3t, const float* __restrict__ be3,
          float* __restrict__ lgt) {
    __shared__ __align__(16) unsigned short SMEM[2 * 16384 + 2 * 4096];  // 80 KiB
    unsigned short* As = SMEM;
    unsigned short* Bs = SMEM + 2 * 16384;
    const int t = threadIdx.x, lane = t & 63, w = t >> 6;
    const int coff = a_src_chunk(lane);
    const int r0l = w * 32 + (lane >> 3);
    const int nt = blockIdx.x & 7, mt = blockIdx.x >> 3;
    const int e = tile_expert[mt]; if (e < 0) return;
    const unsigned short* g0 = h2 + (size_t)(mt * 256 + r0l) * H_ + coff;
    gemm3<64>(g0, g0 + (size_t)8 * H_, g0 + (size_t)16 * H_, g0 + (size_t)24 * H_,
              We3t + (size_t)e * 524288 + (size_t)(nt * 64) * 1024, 1024,
              be3 + (size_t)e * A_ + nt * 64,
              nullptr, lgt + (size_t)(mt * 256) * A_ + nt * 64, A_, 0, As, Bs);
}

// ---------------- head epilogue bodies ----------------
__device__ __forceinline__ void opt_body(int b, const unsigned short* __restrict__ h,
                                         const float* __restrict__ Wo2, const float* __restrict__ bo2,
                                         float* __restrict__ out, float* sm) {
    const int t = threadIdx.x;
    float acc[E_];
#pragma unroll
    for (int j = 0; j < E_; ++j) acc[j] = 0.f;
    for (int k = t; k < H_; k += 256) {
        float hv = bf2f(h[(size_t)b * H_ + k]);
#pragma unroll
        for (int j = 0; j < E_; ++j) acc[j] = fmaf(hv, Wo2[k * E_ + j], acc[j]);
    }
#pragma unroll
    for (int j = 0; j < E_; ++j)
        for (int off = 32; off; off >>= 1) acc[j] += __shfl_down(acc[j], off, 64);
    float* red = sm;
    float* probs = sm + 4 * E_;
    int wave = t >> 6, lane = t & 63;
    if (lane == 0)
        for (int j = 0; j < E_; ++j) red[wave * E_ + j] = acc[j];
    __syncthreads();
    if (t == 0) {
        float z[E_]; float m = -1e30f;
        for (int j = 0; j < E_; ++j) {
            z[j] = red[j] + red[E_ + j] + red[2 * E_ + j] + red[3 * E_ + j] + bo2[j];
            m = fmaxf(m, z[j]);
        }
        float s = 0.f;
        for (int j = 0; j < E_; ++j) { z[j] = expf(z[j] - m); s += z[j]; }
        float inv = 1.f / s;
        for (int j = 0; j < E_; ++j) probs[j] = z[j] * inv;
    }
    __syncthreads();
    if (t < E_) out[(size_t)b * E_ + t] = probs[t];
}

__device__ __forceinline__ void term_body(int b, const unsigned short* __restrict__ h,
                                          const float* __restrict__ Wt2, const float* __restrict__ bt2,
                                          float* __restrict__ out, float* sm) {
    const int t = threadIdx.x;
    float acc = 0.f;
    for (int k = t; k < H_; k += 256) acc = fmaf(bf2f(h[(size_t)b * H_ + k]), Wt2[k], acc);
    for (int off = 32; off; off >>= 1) acc += __shfl_down(acc, off, 64);
    if ((t & 63) == 0) sm[t >> 6] = acc;
    __syncthreads();
    if (t == 0) {
        float z = sm[0] + sm[1] + sm[2] + sm[3] + bt2[0];
        out[b] = 1.f / (1.f + expf(-z));
    }
}

// ---------------- gather + head epilogues, one dispatch (3*B_ blocks x 256) ----------------
__global__ __launch_bounds__(256)
void k_gather(const float* __restrict__ logits, const int* __restrict__ pos_of_row,
              const int* __restrict__ sel,
              float* __restrict__ out_probs, float* __restrict__ out_selopt,
              float* __restrict__ out_selact,
              int* __restrict__ rowlist2, int* __restrict__ cur2,
              const unsigned short* __restrict__ hopt, const float* __restrict__ Wo2,
              const float* __restrict__ bo2, float* __restrict__ out_opt,
              const unsigned short* __restrict__ hterm, const float* __restrict__ Wt2,
              const float* __restrict__ bt2, float* __restrict__ out_term) {
    __shared__ float smbuf[5 * E_ + 8];
    const int bid = blockIdx.x;
    if (bid >= 2 * B_) { term_body(bid - 2 * B_, hterm, Wt2, bt2, out_term, smbuf); return; }
    if (bid >= B_)     { opt_body(bid - B_, hopt, Wo2, bo2, out_opt, smbuf); return; }

    const int b = bid;
    int p = pos_of_row[b];
    if (p < 0) p = 0; if (p >= PB) p = PB - 1;
    const int t = threadIdx.x;
    const float* L = logits + (size_t)p * A_;
    float v0 = L[t], v1 = L[t + 256];

    float bv; int bi;
    if (v0 >= v1) { bv = v0; bi = t; } else { bv = v1; bi = t + 256; }
    for (int off = 32; off; off >>= 1) {
        float ov = __shfl_down(bv, off, 64);
        int   oi = __shfl_down(bi, off, 64);
        if (ov > bv || (ov == bv && oi < bi)) { bv = ov; bi = oi; }
    }
    __shared__ float rv[4]; __shared__ int ri[4];
    int wave = t >> 6, lane = t & 63;
    if (lane == 0) { rv[wave] = bv; ri[wave] = bi; }
    __syncthreads();
    __shared__ float sM; __shared__ int sBi;
    if (t == 0) {
        float mv = rv[0]; int mi = ri[0];
        for (int w = 1; w < 4; ++w)
            if (rv[w] > mv || (rv[w] == mv && ri[w] < mi)) { mv = rv[w]; mi = ri[w]; }
        sM = mv; sBi = mi;
    }
    __syncthreads();
    const float M = sM; const int BI = sBi;

    float e0 = expf(v0 - M), e1 = expf(v1 - M);
    float s = e0 + e1;
    for (int off = 32; off; off >>= 1) s += __shfl_down(s, off, 64);
    __shared__ float reds[4];
    if (lane == 0) reds[wave] = s;
    __syncthreads();
    float inv = 1.f / (reds[0] + reds[1] + reds[2] + reds[3]);

    out_probs[(size_t)b * A_ + t]       = e0 * inv;
    out_probs[(size_t)b * A_ + t + 256] = e1 * inv;

    float s0 = (t == BI) ? -1e30f : v0;
    float s1 = (t + 256 == BI) ? -1e30f : v1;
    float sm = fmaxf(s0, s1);
    for (int off = 32; off; off >>= 1) sm = fmaxf(sm, __shfl_down(sm, off, 64));
    __shared__ float red2[4];
    if (lane == 0) red2[wave] = sm;
    __syncthreads();

    if (t == 0) {
        float second = fmaxf(fmaxf(red2[0], red2[1]), fmaxf(red2[2], red2[3]));
        out_selact[b] = (float)BI;
        int e = sel[b]; e = e < 0 ? 0 : (e >= E_ ? E_ - 1 : e);
        out_selopt[b] = (float)sel[b];
        if (M - second < MARGIN) {
            int pos = atomicAdd(&cur2[e], 1);
            if (pos < FB_CAP) rowlist2[e * FB_CAP + pos] = b;
        }
    }
}

// ---------------- fp32 fallback GEMM, K-split partials: 64x64 tile, BK=32 (R15-proven) ----------------
#define BM 64
#define BN 64
#define BK 32

__global__ __launch_bounds__(256)
void k_pgemm(const float* __restrict__ A, int lda, const int* __restrict__ flags,
             int gather, const float* __restrict__ W,
             float* __restrict__ P, int K, int N) {
    __shared__ float As_[BK][BM + 4];
    __shared__ float Bs_[BK][BN];

    const int mt = blockIdx.y, nt = blockIdx.x, kz = blockIdx.z;
    if (flags[mt * BM] < 0) return;
    const int e = mt >> 1;
    const float* Wb = W + (size_t)e * K * N + (size_t)nt * BN;

    const int t  = threadIdx.x;
    const int tx = t & 15;
    const int ty = t >> 4;

    const int arow = t >> 3;
    const int ak   = (t & 7) * 4;
    int r0 = mt * BM + arow, r1 = r0 + 32;
    if (gather) { r0 = flags[r0]; r1 = flags[r1]; }
    const int bkr = t >> 4;
    const int bn  = (t & 15) * 4;

    float acc[4][4];
#pragma unroll
    for (int i = 0; i < 4; ++i)
#pragma unroll
        for (int j = 0; j < 4; ++j) acc[i][j] = 0.0f;

    const int kbeg = kz * (K / KSPLIT);
    const int kend = kbeg + (K / KSPLIT);
    for (int k0 = kbeg; k0 < kend; k0 += BK) {
        float4 a0 = make_float4(0.f, 0.f, 0.f, 0.f), a1 = a0;
        if (r0 >= 0) a0 = *(const float4*)&A[(size_t)r0 * lda + k0 + ak];
        if (r1 >= 0) a1 = *(const float4*)&A[(size_t)r1 * lda + k0 + ak];
        float4 b0 = *(const float4*)&Wb[(size_t)(k0 + bkr) * N + bn];
        float4 b1 = *(const float4*)&Wb[(size_t)(k0 + bkr + 16) * N + bn];

        __syncthreads();
        As_[ak + 0][arow] = a0.x; As_[ak + 1][arow] = a0.y;
        As_[ak + 2][arow] = a0.z; As_[ak + 3][arow] = a0.w;
        As_[ak + 0][arow + 32] = a1.x; As_[ak + 1][arow + 32] = a1.y;
        As_[ak + 2][arow + 32] = a1.z; As_[ak + 3][arow + 32] = a1.w;
        *(float4*)&Bs_[bkr][bn]      = b0;
        *(float4*)&Bs_[bkr + 16][bn] = b1;
        __syncthreads();

#pragma unroll
        for (int kk = 0; kk < BK; ++kk) {
            const float4 av = *(const float4*)&As_[kk][ty * 4];
            const float4 bv = *(const float4*)&Bs_[kk][tx * 4];
            const float a_[4] = {av.x, av.y, av.z, av.w};
            const float b_[4] = {bv.x, bv.y, bv.z, bv.w};
#pragma unroll
            for (int i = 0; i < 4; ++i)
#pragma unroll
                for (int j = 0; j < 4; ++j)
                    acc[i][j] = fmaf(a_[i], b_[j], acc[i][j]);
        }
    }

    float* Pz = P + (size_t)kz * FROWS * N;
    const int n0 = nt * BN + tx * 4;
#pragma unroll
    for (int i = 0; i < 4; ++i) {
        int m = mt * BM + ty * 4 + i;
        *(float4*)&Pz[(size_t)m * N + n0] = make_float4(acc[i][0], acc[i][1], acc[i][2], acc[i][3]);
    }
}

// ---------------- fallback reduce: sum K-split partials + bias (+relu) ----------------
__global__ __launch_bounds__(256)
void k_fred(const float* __restrict__ P, const int* __restrict__ flags,
            const float* __restrict__ bias, float* __restrict__ C, int N, int relu) {
    const int m = blockIdx.x;
    if (flags[m] < 0) return;
    const int e = m >> 7;
    const int t = threadIdx.x;
    if (t * 4 >= N) return;
    const size_t MN = (size_t)FROWS * N;
    const size_t base = (size_t)m * N + t * 4;
    float4 s = *(const float4*)&P[base];
#pragma unroll
    for (int z = 1; z < KSPLIT; ++z) {
        float4 p = *(const float4*)&P[(size_t)z * MN + base];
        s.x += p.x; s.y += p.y; s.z += p.z; s.w += p.w;
    }
    const float* bp = bias + (size_t)e * N + t * 4;
    s.x += bp[0]; s.y += bp[1]; s.z += bp[2]; s.w += bp[3];
    if (relu) {
        s.x = fmaxf(s.x, 0.f); s.y = fmaxf(s.y, 0.f);
        s.z = fmaxf(s.z, 0.f); s.w = fmaxf(s.w, 0.f);
    }
    *(float4*)&C[base] = s;
}

// ---------------- fixup: fp32 softmax+argmax for flagged rows ----------------
__global__ __launch_bounds__(256)
void k_fixup(const float* __restrict__ logitsf, const int* __restrict__ rowlist2,
             float* __restrict__ out_probs, float* __restrict__ out_selact) {
    const int i = blockIdx.x;
    const int row = rowlist2[i];
    if (row < 0) return;
    const int t = threadIdx.x;
    const float* L = logitsf + (size_t)i * A_;
    float v0 = L[t], v1 = L[t + 256];

    float bv; int bi;
    if (v0 >= v1) { bv = v0; bi = t; } else { bv = v1; bi = t + 256; }
    for (int off = 32; off; off >>= 1) {
        float ov = __shfl_down(bv, off, 64);
        int   oi = __shfl_down(bi, off, 64);
        if (ov > bv || (ov == bv && oi < bi)) { bv = ov; bi = oi; }
    }
    __shared__ float rv[4]; __shared__ int ri[4];
    int wave = t >> 6, lane = t & 63;
    if (lane == 0) { rv[wave] = bv; ri[wave] = bi; }
    __syncthreads();
    __shared__ float sM; __shared__ int sBi;
    if (t == 0) {
        float mv = rv[0]; int mi = ri[0];
        for (int w = 1; w < 4; ++w)
            if (rv[w] > mv || (rv[w] == mv && ri[w] < mi)) { mv = rv[w]; mi = ri[w]; }
        sM = mv; sBi = mi;
    }
    __syncthreads();

    float e0 = expf(v0 - sM), e1 = expf(v1 - sM);
    float s = e0 + e1;
    for (int off = 32; off; off >>= 1) s += __shfl_down(s, off, 64);
    __shared__ float reds[4];
    if (lane == 0) reds[wave] = s;
    __syncthreads();
    float inv = 1.f / (reds[0] + reds[1] + reds[2] + reds[3]);

    out_probs[(size_t)row * A_ + t]       = e0 * inv;
    out_probs[(size_t)row * A_ + t + 256] = e1 * inv;
    if (t == 0) out_selact[row] = (float)sBi;
}

extern "C" void kernel_launch(void* const* d_in, const int* in_sizes, int n_in,
                              void* d_out, int out_size, void* d_ws, size_t ws_size,
                              hipStream_t stream) {
    const float* state = (const float*)d_in[0];
    const int*   sel   = (const int*)d_in[1];
    const float* Wo1 = (const float*)d_in[2];
    const float* bo1 = (const float*)d_in[3];
    const float* Wo2 = (const float*)d_in[4];
    const float* bo2 = (const float*)d_in[5];
    const float* We1 = (const float*)d_in[6];
    const float* be1 = (const float*)d_in[7];
    const float* We2 = (const float*)d_in[8];
    const float* be2 = (const float*)d_in[9];
    const float* We3 = (const float*)d_in[10];
    const float* be3 = (const float*)d_in[11];
    const float* Wt1 = (const float*)d_in[12];
    const float* bt1 = (const float*)d_in[13];
    const float* Wt2 = (const float*)d_in[14];
    const float* bt2 = (const float*)d_in[15];
    float* out = (float*)d_out;          // float32 outputs (established R3)

    // ---- workspace: 64K meta + P0(12.58M) + P1(16.78M) + P2(12.58M) + W1(16.78M) + W2(16.78M) = 75.6 MB ----
    // Lifetimes: P0: {Sbf+Wbf}(prep..D2) -> h2b(D3..D5) -> h1f/h2f/lgf (fallback)
    //            P1: {hopt,hterm}(D2..gather) -> Pbuf (fallback)
    //            P2: h1b(D2..D3) -> lgt(D5..gather)
    //            W1: We1t(prep..D2) -> We3t(D3..D5)
    //            W2: We2t(D2..D3)
    char* w = (char*)d_ws;
    int* meta        = (int*)w;
    int* rowlist     = meta;               // [6144]
    int* pos_of_row  = meta + 6144;        // [4096]
    int* rowlist2    = meta + 10240;       // [1024]
    int* tile_expert = meta + 11264;       // [32]
    int* cur2        = meta + 11296;       // [16]
    char* P0 = w + 65536;                  // 12,582,912 B
    char* P1 = P0 + 12582912;              // 16,777,216 B
    char* P2 = P1 + 16777216;              // 12,582,912 B
    char* W1 = P2 + 12582912;              // 16,777,216 B
    char* W2 = W1 + 16777216;              // 16,777,216 B
    unsigned short* Sbf   = (unsigned short*)P0;
    unsigned short* Wbf   = (unsigned short*)(P0 + (8u << 20));
    unsigned short* h2b   = (unsigned short*)P0;
    unsigned short* hopt  = (unsigned short*)P1;
    unsigned short* hterm = hopt + (size_t)B_ * H_;
    unsigned short* h1b   = (unsigned short*)P2;
    unsigned short* We1t  = (unsigned short*)W1;
    unsigned short* We3t  = (unsigned short*)W1;          // reuses W1 after D2
    unsigned short* We2t  = (unsigned short*)W2;
    float* lgt  = (float*)P2;                             // 12.58MB exact
    float* Pbuf = (float*)P1;                             // 16MB
    float* h1f  = (float*)P0;                             // 4MB
    float* h2f  = h1f + (size_t)FROWS * H_;               // 4MB
    float* lgf  = h2f + (size_t)FROWS * H_;               // 2MB

    size_t act_off    = (size_t)B_ * E_;
    size_t term_off   = act_off + (size_t)B_ * A_;
    size_t selopt_off = term_off + B_;
    size_t selact_off = selopt_off + B_;

    // ---- prep: bucketize + state->bf16 + head-W^T->bf16 + We1^T->bf16 ----
    k_prep<<<5377, 256, 0, stream>>>(state, Sbf, Wo1, Wt1, Wbf, We1, We1t,
                                     sel, tile_expert, rowlist, pos_of_row, rowlist2, cur2);

    // ---- D2: heads + expert L1 (224 GEMM blocks) + We2^T (512 blocks on spare CUs) ----
    k_d2<<<736, 512, 0, stream>>>(Sbf, rowlist, tile_expert, Wbf,
                                  bo1, bt1, We1t, be1, We2, We2t, hopt, hterm, h1b);
    // ---- D3: expert L2 (192 GEMM blocks) + We3^T (256 blocks) ----
    k_d3<<<448, 512, 0, stream>>>(h1b, tile_expert, We2t, be2, We3, We3t, h2b);
    // ---- D5: expert L3 -> fp32 logits into P2 (h1b dead) ----
    k_d5<<<192, 512, 0, stream>>>(h2b, tile_expert, We3t, be3, lgt);

    // ---- gather + head epilogues (one dispatch; hopt/hterm still live in P1) ----
    k_gather<<<3 * B_, 256, 0, stream>>>(lgt, pos_of_row, sel,
                                         out + act_off, out + selopt_off, out + selact_off,
                                         rowlist2, cur2,
                                         hopt, Wo2, bo2, out,
                                         hterm, Wt2, bt2, out + term_off);

    // ---- fp32 fallback chain (R15-proven: pgemm + fred per layer) ----
    k_pgemm<<<dim3(H_ / BN, FROWS / BM, KSPLIT), 256, 0, stream>>>(state, D_, rowlist2, 1, We1, Pbuf, D_, H_);
    k_fred<<<FROWS, 256, 0, stream>>>(Pbuf, rowlist2, be1, h1f, H_, 1);
    k_pgemm<<<dim3(H_ / BN, FROWS / BM, KSPLIT), 256, 0, stream>>>(h1f, H_, rowlist2, 0, We2, Pbuf, H_, H_);
    k_fred<<<FROWS, 256, 0, stream>>>(Pbuf, rowlist2, be2, h2f, H_, 1);
    k_pgemm<<<dim3(A_ / BN, FROWS / BM, KSPLIT), 256, 0, stream>>>(h2f, H_, rowlist2, 0, We3, Pbuf, H_, A_);
    k_fred<<<FROWS, 256, 0, stream>>>(Pbuf, rowlist2, be3, lgf, A_, 0);
    k_fixup<<<FROWS, 256, 0, stream>>>(lgf, rowlist2, out + act_off, out + selact_off);
}